// Round 7
// baseline (480.095 us; speedup 1.0000x reference)
//
#include <hip/hip_runtime.h>
#include <hip/hip_bf16.h>
#include <type_traits>

#define DIN   7686
#define NNODE 7946
#define HOUT  260
#define KP    8192   // padded k (64 chunks of 128)

typedef __attribute__((ext_vector_type(8))) short bf16x8;
typedef __attribute__((ext_vector_type(4))) float f32x4;

__device__ __forceinline__ unsigned int f2b(float f) {
  union { float f; unsigned int u; } v; v.f = f;
  return (v.u + 0x7FFFu + ((v.u >> 16) & 1u)) >> 16;  // RNE float->bf16
}
__device__ __forceinline__ unsigned int pack2(float lo, float hi) {
  unsigned int r;
  asm("v_cvt_pk_bf16_f32 %0, %1, %2" : "=v"(r) : "v"(lo), "v"(hi));
  return r;
}
__device__ __forceinline__ float b2f(unsigned short h) {
  union { unsigned int u; float f; } v; v.u = ((unsigned int)h) << 16; return v.f;
}
__device__ __forceinline__ float readlane_f(float v, int lane) {
  return __uint_as_float(__builtin_amdgcn_readlane(__float_as_uint(v), lane));
}

// ---------------------------------------------------------------------------
// prep_x2: fp32 X -> bf16, FRAGMENT-MAJOR layout for direct MFMA A-loads:
// block(kc 0..63, i16 0..15, ks 0..3) = 1KB at ((kc*16+i16)*4+ks)*1024.
// lane l slot (16B): m = i16*16 + (l&15), k = kc*128 + ks*32 + (l>>4)*8 .. +8
// ---------------------------------------------------------------------------
__global__ void prep_x2(const float* __restrict__ X, char* __restrict__ XbT2)
{
  const int m = blockIdx.x, t = threadIdx.x;
  const float* row = X + (size_t)m * DIN;
  const int i16 = m >> 4;
#pragma unroll
  for (int c2 = 0; c2 < 4; ++c2) {
    const int k8 = (c2 * 256 + t) * 8;
    float f[8];
    if (k8 + 8 <= DIN) {
#pragma unroll
      for (int h = 0; h < 4; ++h) {
        float2 v = *(const float2*)(row + k8 + h * 2);
        f[h * 2] = v.x; f[h * 2 + 1] = v.y;
      }
    } else {
#pragma unroll
      for (int h = 0; h < 8; ++h) f[h] = (k8 + h < DIN) ? row[k8 + h] : 0.f;
    }
    uint4 o;
    o.x = pack2(f[0], f[1]); o.y = pack2(f[2], f[3]);
    o.z = pack2(f[4], f[5]); o.w = pack2(f[6], f[7]);
    const int kc = k8 >> 7, kk = k8 & 127, ks = kk >> 5, hq = (kk & 31) >> 3;
    const int lane = (m & 15) + (hq << 4);
    char* dst = XbT2 + ((((size_t)kc * 16 + i16) * 4 + ks) << 10) + lane * 16;
    *(uint4*)dst = o;
  }
}

// ---------------------------------------------------------------------------
// gemm_qk3: P[m,n] = sum_k X[m,k]*W[n,k], K-split x2, bf16 partials.
// BM=256 BN=64 BK=128, 32 steps per z-half. 512 thr = 8 waves (4wr x 2wc).
// B: 4-deep NAMED register ring (R0..R3) -> bf16 LDS chunks (1040B padded,
//    2-way banks). NO vmcnt drains: compiler-counted waits only; raw
//    s_barrier with lgkmcnt(0). A: direct 1KB wave-contiguous global loads
//    from fragment-major XbT2 (L2-resident). LDS 33KB -> 2 WGs/CU.
// ---------------------------------------------------------------------------
__global__ __launch_bounds__(512, 4)
void gemm_qk3(const char* __restrict__ XbT2,
              const float* __restrict__ Wq, const float* __restrict__ Wk,
              unsigned short* __restrict__ PQK)
{
  const int mat = blockIdx.y, z = blockIdx.z;
  const float* W = mat ? Wk : Wq;
  const int n0 = blockIdx.x * 64;
  const int tid = threadIdx.x, l = tid & 63, wv = tid >> 6;
  const int wr = wv >> 1, wc = wv & 1;
  const int lm = l & 15, hq = l >> 4;

  __shared__ __align__(16) char Bs[2][16 * 1040];   // 2 x 16.25KB

  // B staging map: row br = tid>>3 (64 rows), q = tid&7; chunks {q, q+8},
  // chunk c8 = 8 consecutive floats at k-local c8*8 (load as 4 float2).
  const int br = tid >> 3, q = tid & 7;
  int bn = n0 + br; if (bn > DIN - 1) bn = DIN - 1;
  const long long bbase = (long long)bn * DIN;
  const long long bMax = (long long)DIN * DIN - 2;
  const int kcBase = z * 32;

  float2 R0[8], R1[8], R2[8], R3[8];

#define LOADB(SET, s) {                                                  \
    const long long kg = bbase + (long long)(kcBase + (s)) * 128;        \
    _Pragma("unroll")                                                    \
    for (int c = 0; c < 2; ++c)                                          \
      _Pragma("unroll")                                                  \
      for (int h = 0; h < 4; ++h) {                                      \
        long long idx = kg + (q + c * 8) * 8 + h * 2;                    \
        if (idx > bMax) idx = bMax;                                      \
        SET[c * 4 + h] = *(const float2*)(W + idx);                      \
      } }

#define SWRITE(buf, SET) {                                               \
    char* bs_ = Bs[buf];                                                 \
    _Pragma("unroll")                                                    \
    for (int c = 0; c < 2; ++c) {                                        \
      uint4 o_;                                                          \
      o_.x = pack2(SET[c*4+0].x, SET[c*4+0].y);                          \
      o_.y = pack2(SET[c*4+1].x, SET[c*4+1].y);                          \
      o_.z = pack2(SET[c*4+2].x, SET[c*4+2].y);                          \
      o_.w = pack2(SET[c*4+3].x, SET[c*4+3].y);                          \
      *(uint4*)(bs_ + (q + c * 8) * 1040 + br * 16) = o_;                \
    } }

  f32x4 acc[4][2] = {};

#define COMPUTE(buf, s) {                                                \
    const int kc_ = kcBase + (s);                                        \
    bf16x8 a_[4][4];                                                     \
    _Pragma("unroll")                                                    \
    for (int i = 0; i < 4; ++i)                                          \
      _Pragma("unroll")                                                  \
      for (int ks = 0; ks < 4; ++ks)                                     \
        a_[i][ks] = *(const bf16x8*)(XbT2 +                              \
          ((((size_t)kc_ * 16 + (wr * 4 + i)) * 4 + ks) << 10) + l * 16);\
    const char* bs_ = Bs[buf];                                           \
    _Pragma("unroll")                                                    \
    for (int ks = 0; ks < 4; ++ks) {                                     \
      bf16x8 bf_[2];                                                     \
      _Pragma("unroll")                                                  \
      for (int j = 0; j < 2; ++j) {                                      \
        const int n_ = wc * 32 + j * 16 + lm;                            \
        bf_[j] = *(const bf16x8*)(bs_ + (ks * 4 + hq) * 1040 + n_ * 16); \
      }                                                                  \
      _Pragma("unroll")                                                  \
      for (int i = 0; i < 4; ++i) {                                      \
        acc[i][0] = __builtin_amdgcn_mfma_f32_16x16x32_bf16(a_[i][ks], bf_[0], acc[i][0], 0, 0, 0); \
        acc[i][1] = __builtin_amdgcn_mfma_f32_16x16x32_bf16(a_[i][ks], bf_[1], acc[i][1], 0, 0, 0); \
      }                                                                  \
    } }

// raw barrier: LDS drain only — vm queue (B-ring) stays in flight across it
#define BAR() { asm volatile("s_waitcnt lgkmcnt(0)" ::: "memory");       \
                __builtin_amdgcn_sched_barrier(0);                       \
                __builtin_amdgcn_s_barrier();                            \
                __builtin_amdgcn_sched_barrier(0); }

#define STEP(s, NS) {                                                    \
    if ((s) + 1 < 32) SWRITE(((s) + 1) & 1, NS)                          \
    COMPUTE((s) & 1, (s))                                                \
    if ((s) + 5 < 32) LOADB(NS, (s) + 5)                                 \
    BAR() }

  // prologue: ring <- steps 0..3; stage step 0; refill R0 <- step 4
  LOADB(R0, 0) LOADB(R1, 1) LOADB(R2, 2) LOADB(R3, 3)
  SWRITE(0, R0)
  LOADB(R0, 4)
  BAR()

  for (int su = 0; su < 32; su += 4) {
    STEP(su + 0, R1)
    STEP(su + 1, R2)
    STEP(su + 2, R3)
    STEP(su + 3, R0)
  }
#undef LOADB
#undef SWRITE
#undef COMPUTE
#undef BAR
#undef STEP

  // epilogue: bf16 partial (no bias) for this (mat, z)
  unsigned short* Cp = PQK + (size_t)(mat * 2 + z) * 256 * KP;
#pragma unroll
  for (int i = 0; i < 4; ++i) {
    const int r0 = wr * 64 + i * 16 + (l >> 4) * 4;
#pragma unroll
    for (int j = 0; j < 2; ++j) {
      const int col = n0 + wc * 32 + j * 16 + lm;
#pragma unroll
      for (int qq = 0; qq < 4; ++qq)
        Cp[(size_t)(r0 + qq) * KP + col] = (unsigned short)f2b(acc[i][j][qq]);
    }
  }
}

// ---------------------------------------------------------------------------
// reduce 2 bf16 partials + bias -> Qbf/Kbf bf16 [256][KP], pads zeroed
// grid (64, 2) x 128 threads
// ---------------------------------------------------------------------------
__global__ void reduce_qk3(const unsigned short* __restrict__ PQK,
                           const float* __restrict__ bq, const float* __restrict__ bk,
                           unsigned short* __restrict__ Qbf, unsigned short* __restrict__ Kbf)
{
  const int mat = blockIdx.y;
  const int c = blockIdx.x * 128 + threadIdx.x;
  const float* bias = mat ? bk : bq;
  const bool valid = c < DIN;
  const float bb = valid ? bias[c] : 0.f;
  const unsigned short* P0 = PQK + (size_t)(mat * 2 + 0) * 256 * KP + c;
  const unsigned short* P1 = PQK + (size_t)(mat * 2 + 1) * 256 * KP + c;
  unsigned short* O = (mat ? Kbf : Qbf) + c;
#pragma unroll 4
  for (int r = 0; r < 256; ++r) {
    float v = b2f(P0[(size_t)r * KP]) + b2f(P1[(size_t)r * KP]) + bb;
    if (!valid) v = 0.f;
    O[(size_t)r * KP] = (unsigned short)f2b(v);
  }
}

// ---------------------------------------------------------------------------
// logits partials: LP[z][m][n] = sum_{k in chunk z} Q[m,k]*K[n,k]
// ---------------------------------------------------------------------------
__global__ __launch_bounds__(512)
void gemm_logits(const unsigned short* __restrict__ Qbf,
                 const unsigned short* __restrict__ Kbf, float* __restrict__ LP)
{
  const int qr = blockIdx.x & 1, qc = blockIdx.x >> 1, z = blockIdx.z;
  const int tid = threadIdx.x, lane = tid & 63, wv = tid >> 6;
  const int lm = lane & 15, lq = (lane >> 4) * 8;
  const int rowBase = qr * 128 + (wv & 3) * 32;
  const int colBase = qc * 128 + (wv >> 2) * 64;
  const int k0 = z * 128;
  f32x4 acc[2][4] = {};
#pragma unroll
  for (int ks = 0; ks < 4; ++ks) {
    bf16x8 a[2], b[4];
#pragma unroll
    for (int i = 0; i < 2; ++i)
      a[i] = *(const bf16x8*)(Qbf + (size_t)(rowBase + i * 16 + lm) * KP + k0 + ks * 32 + lq);
#pragma unroll
    for (int j = 0; j < 4; ++j)
      b[j] = *(const bf16x8*)(Kbf + (size_t)(colBase + j * 16 + lm) * KP + k0 + ks * 32 + lq);
#pragma unroll
    for (int i = 0; i < 2; ++i)
#pragma unroll
      for (int j = 0; j < 4; ++j)
        acc[i][j] = __builtin_amdgcn_mfma_f32_16x16x32_bf16(a[i], b[j], acc[i][j], 0, 0, 0);
  }
  float* out = LP + (size_t)z * 65536;
#pragma unroll
  for (int i = 0; i < 2; ++i) {
    const int r0 = rowBase + i * 16 + (lane >> 4) * 4;
#pragma unroll
    for (int j = 0; j < 4; ++j) {
      const int col = colBase + j * 16 + lm;
#pragma unroll
      for (int q = 0; q < 4; ++q)
        out[(size_t)(r0 + q) * 256 + col] = acc[i][j][q];
    }
  }
}

// ---------------------------------------------------------------------------
// fused: sum 64 logit partials -> row softmax -> atomicAdd into abar (w/ 1/256)
// ---------------------------------------------------------------------------
__global__ void softmax_fused(const float* __restrict__ LP, float* __restrict__ abar)
{
  __shared__ float red[8];
  const int m = blockIdx.x, t = threadIdx.x;
  float v = 0.f;
#pragma unroll 8
  for (int zz = 0; zz < 64; ++zz) v += LP[(size_t)zz * 65536 + m * 256 + t];
  const float scale = 1.0f / sqrtf((float)DIN);
  float mx = v;
#pragma unroll
  for (int o = 32; o >= 1; o >>= 1) mx = fmaxf(mx, __shfl_xor(mx, o, 64));
  if ((t & 63) == 0) red[t >> 6] = mx;
  __syncthreads();
  mx = fmaxf(fmaxf(red[0], red[1]), fmaxf(red[2], red[3]));
  float e = __expf((v - mx) * scale);
  float s = e;
#pragma unroll
  for (int o = 32; o >= 1; o >>= 1) s += __shfl_xor(s, o, 64);
  if ((t & 63) == 0) red[4 + (t >> 6)] = s;
  __syncthreads();
  s = red[4] + red[5] + red[6] + red[7];
  atomicAdd(&abar[t], e * (1.0f / 256.0f) / s);
}

// y[c] = sum_m abar[m] * X[m][c]
__global__ void y_kernel(const float* __restrict__ X, const float* __restrict__ abar,
                         float* __restrict__ y)
{
  __shared__ float ab[256];
  ab[threadIdx.x] = abar[threadIdx.x];
  __syncthreads();
  const int c = blockIdx.x * 256 + threadIdx.x;
  if (c >= DIN) return;
  float s = 0.f;
#pragma unroll 8
  for (int m = 0; m < 256; ++m) s += ab[m] * X[(size_t)m * DIN + c];
  y[c] = s;
}

// ctx[d] = Wv[d,:]·y + bv[d] — one row per wave, lane-contiguous float2 stream
__global__ __launch_bounds__(512)
void ctx_mv(const float* __restrict__ Wv, const float* __restrict__ y,
            const float* __restrict__ bv, float* __restrict__ ctx)
{
  const int wv = threadIdx.x >> 6, l = threadIdx.x & 63;
  const int row = blockIdx.x * 8 + wv;
  if (row >= DIN) return;
  const float* wr_ = Wv + (size_t)row * DIN;
  float s = 0.f;
  for (int it = 0; it < 61; ++it) {
    const int k = it * 128 + l * 2;
    if (k < DIN) {
      float2 w2 = *(const float2*)(wr_ + k);
      float2 y2 = *(const float2*)(y + k);
      s = fmaf(w2.x, y2.x, s);
      s = fmaf(w2.y, y2.y, s);
    }
  }
#pragma unroll
  for (int o = 32; o >= 1; o >>= 1) s += __shfl_xor(s, o, 64);
  if (l == 0) ctx[row] = s + bv[row];
}

// base[j] += sum_{i in chunk} ctx[i] * (mu+sg*ep)[i][DIN+j]
__global__ void base_kernel(const float* __restrict__ mu, const float* __restrict__ sg,
                            const float* __restrict__ ep, const float* __restrict__ ctx,
                            float* __restrict__ base)
{
  const int j = threadIdx.x;
  if (j >= HOUT) return;
  const int i0 = blockIdx.x * 31;
  const int i1 = min(i0 + 31, DIN);
  float acc = 0.f;
#pragma unroll 4
  for (int i = i0; i < i1; ++i) {
    const size_t idx = (size_t)i * NNODE + DIN + j;
    acc = fmaf(ctx[i], fmaf(sg[idx], ep[idx], mu[idx]), acc);
  }
  atomicAdd(&base[j], acc);
}

// WsG[t][j] = (mu+sg*ep)[DIN+t][DIN+j]
__global__ void ws_kernel(const float* __restrict__ mu, const float* __restrict__ sg,
                          const float* __restrict__ ep, float* __restrict__ WsG)
{
  const int t = blockIdx.x;
  const int j = threadIdx.x;
  if (j >= HOUT) return;
  const size_t idx = (size_t)(DIN + t) * NNODE + DIN + j;
  WsG[t * HOUT + j] = fmaf(sg[idx], ep[idx], mu[idx]);
}

// ---------------------------------------------------------------------------
// scan2: latency-minimal sequential NEAT scan. 1 wave.
// ---------------------------------------------------------------------------
__global__ __launch_bounds__(64, 1)
void scan2(const float* __restrict__ WsG, const float* __restrict__ base,
           const float* __restrict__ bmu, const float* __restrict__ bsg,
           const float* __restrict__ epb, float* __restrict__ out)
{
  __shared__ __align__(16) float tile[32 * HOUT + 128];
  const int l = threadIdx.x;

  float a0, a1, a2, a3, a4;
  {
    int j = l;       a0 = base[j] + bmu[j] + bsg[j] * epb[j];
    j = l + 64;      a1 = base[j] + bmu[j] + bsg[j] * epb[j];
    j = l + 128;     a2 = base[j] + bmu[j] + bsg[j] * epb[j];
    j = l + 192;     a3 = base[j] + bmu[j] + bsg[j] * epb[j];
    j = l + 256;     a4 = (j < HOUT) ? (base[j] + bmu[j] + bsg[j] * epb[j]) : 0.f;
  }

  float4 stg[33];
  auto LOADT = [&](int tb) {
    const int nfl = ((tb == 8) ? 4 : 32) * HOUT;
    const float* src = WsG + tb * 32 * HOUT;
#pragma unroll
    for (int c = 0; c < 33; ++c) {
      const int o = c * 256 + l * 4;
      if (o < nfl) stg[c] = *(const float4*)(src + o);
    }
  };
  auto WRITET = [&](int tb) {
    const int nfl = ((tb == 8) ? 4 : 32) * HOUT;
#pragma unroll
    for (int c = 0; c < 33; ++c) {
      const int o = c * 256 + l * 4;
      if (o < nfl) *(float4*)&tile[o] = stg[c];
    }
  };

  float w0, w1, w2, w3, w4;
  auto PRER = [&](int trow) {
    const float* tr = tile + trow * HOUT;
    w0 = tr[l]; w1 = tr[l + 64]; w2 = tr[l + 128]; w3 = tr[l + 192]; w4 = tr[l + 256];
  };

  auto inner = [&](auto Bc, int tb, int nrows) {
    constexpr int B = Bc.value;
    for (int tt = 0; tt < nrows; ++tt) {
      const int t = tb * 32 + tt;
      float pre;
      if constexpr (B == 0) pre = readlane_f(a0, t & 63);
      else if constexpr (B == 1) pre = readlane_f(a1, t & 63);
      else if constexpr (B == 2) pre = readlane_f(a2, t & 63);
      else if constexpr (B == 3) pre = readlane_f(a3, t & 63);
      else pre = readlane_f(a4, t & 63);
      const float pc = fminf(fmaxf(pre, -12.f), 12.f);
      const float e = __expf(2.f * pc);
      const float vt = 1.f - 2.f / (e + 1.f);
      if (t >= 256 && l == 0) out[t - 256] = vt;
      if (l > t)            a0 = fmaf(vt, w0, a0);
      if (l + 64 > t)       a1 = fmaf(vt, w1, a1);
      if (l + 128 > t)      a2 = fmaf(vt, w2, a2);
      if (l + 192 > t)      a3 = fmaf(vt, w3, a3);
      if (l + 256 > t && l + 256 < HOUT) a4 = fmaf(vt, w4, a4);
      if (tt + 1 < nrows) PRER(tt + 1);
    }
  };

  LOADT(0); WRITET(0); PRER(0);

#define TILE_STEP(tb, B, nr)                                    \
  { if ((tb) < 8) LOADT((tb) + 1);                              \
    inner(std::integral_constant<int, B>{}, (tb), (nr));        \
    if ((tb) < 8) { WRITET((tb) + 1); PRER(0); } }

  TILE_STEP(0, 0, 32)
  TILE_STEP(1, 0, 32)
  TILE_STEP(2, 1, 32)
  TILE_STEP(3, 1, 32)
  TILE_STEP(4, 2, 32)
  TILE_STEP(5, 2, 32)
  TILE_STEP(6, 3, 32)
  TILE_STEP(7, 3, 32)
  TILE_STEP(8, 4, 4)
#undef TILE_STEP
}

// ---------------------------------------------------------------------------
extern "C" void kernel_launch(void* const* d_in, const int* in_sizes, int n_in,
                              void* d_out, int out_size, void* d_ws, size_t ws_size,
                              hipStream_t stream)
{
  const float* X   = (const float*)d_in[0];
  const float* Wq  = (const float*)d_in[1];
  const float* bq  = (const float*)d_in[2];
  const float* Wk  = (const float*)d_in[3];
  const float* bk  = (const float*)d_in[4];
  const float* Wv  = (const float*)d_in[5];
  const float* bv  = (const float*)d_in[6];
  const float* wmu = (const float*)d_in[7];
  const float* wsg = (const float*)d_in[8];
  const float* bmu = (const float*)d_in[9];
  const float* bsg = (const float*)d_in[10];
  const float* epw = (const float*)d_in[11];
  const float* epb = (const float*)d_in[12];

  char* p = (char*)d_ws;
  auto alloc = [&](size_t bytes) -> char* {
    char* r = p;
    p += (bytes + 255) & ~(size_t)255;
    return r;
  };
  char* XbT2 = alloc((size_t)64 * 65536);                       // 4MB fragment-major
  unsigned short* PQK = (unsigned short*)alloc((size_t)4 * 256 * KP * 2);  // 16MB
  unsigned short* Qbf = (unsigned short*)alloc((size_t)256 * KP * 2);
  unsigned short* Kbf = (unsigned short*)alloc((size_t)256 * KP * 2);
  float* LP   = (float*)alloc((size_t)64 * 65536 * 4);          // 16MB
  float* abar = (float*)alloc(256 * 4);
  float* y    = (float*)alloc(7686 * 4);
  float* ctx  = (float*)alloc(7686 * 4);
  float* base = (float*)alloc(HOUT * 4);
  float* WsG  = (float*)alloc((size_t)HOUT * HOUT * 4 + 1024);

  prep_x2<<<dim3(256), dim3(256), 0, stream>>>(X, XbT2);
  hipMemsetAsync(abar, 0, 256 * 4, stream);
  hipMemsetAsync(base, 0, HOUT * 4, stream);

  gemm_qk3<<<dim3(121, 2, 2), dim3(512), 0, stream>>>(XbT2, Wq, Wk, PQK);
  reduce_qk3<<<dim3(64, 2), dim3(128), 0, stream>>>(PQK, bq, bk, Qbf, Kbf);
  gemm_logits<<<dim3(4, 1, 64), dim3(512), 0, stream>>>(Qbf, Kbf, LP);
  softmax_fused<<<dim3(256), dim3(256), 0, stream>>>(LP, abar);
  y_kernel<<<dim3(31), dim3(256), 0, stream>>>(X, abar, y);
  ctx_mv<<<dim3(961), dim3(512), 0, stream>>>(Wv, y, bv, ctx);
  base_kernel<<<dim3(256), dim3(320), 0, stream>>>(wmu, wsg, epw, ctx, base);
  ws_kernel<<<dim3(260), dim3(320), 0, stream>>>(wmu, wsg, epw, WsG);
  scan2<<<dim3(1), dim3(64), 0, stream>>>(WsG, base, bmu, bsg, epb, (float*)d_out);
}

// Round 8
// 449.316 us; speedup vs baseline: 1.0685x; 1.0685x over previous
//
#include <hip/hip_runtime.h>
#include <hip/hip_bf16.h>
#include <type_traits>

#define DIN   7686
#define NNODE 7946
#define HOUT  260
#define KP    8192   // padded k for Qbf/Kbf rows
#define NT    121    // k-steps of 64 (121*64 = 7744 >= DIN)

typedef __attribute__((ext_vector_type(8))) short bf16x8;
typedef __attribute__((ext_vector_type(4))) float f32x4;

__device__ __forceinline__ unsigned int f2b(float f) {
  union { float f; unsigned int u; } v; v.f = f;
  return (v.u + 0x7FFFu + ((v.u >> 16) & 1u)) >> 16;  // RNE float->bf16
}
__device__ __forceinline__ unsigned int pack2(float lo, float hi) {
  unsigned int r;
  asm("v_cvt_pk_bf16_f32 %0, %1, %2" : "=v"(r) : "v"(lo), "v"(hi));
  return r;
}
__device__ __forceinline__ float readlane_f(float v, int lane) {
  return __uint_as_float(__builtin_amdgcn_readlane(__float_as_uint(v), lane));
}
__device__ __forceinline__ void gload16(const void* g, void* l) {
  __builtin_amdgcn_global_load_lds(
      (const __attribute__((address_space(1))) unsigned int*)g,
      (__attribute__((address_space(3))) unsigned int*)l, 16, 0, 0);
}

// ---------------------------------------------------------------------------
// prep_x3: fp32 X -> bf16, per-BK=64 tile, XOR-swizzled for conflict-free
// ds_read after linear global_load_lds (T21): tile kc (32KB) holds
// [m=256][64k]: byte = kc*32768 + m*128 + ((kf*2) ^ ((m&7)<<4)). Pads zeroed.
// ---------------------------------------------------------------------------
__global__ void prep_x3(const float* __restrict__ X, char* __restrict__ XbA)
{
  const int m = blockIdx.x, t = threadIdx.x;
  const float* row = X + (size_t)m * DIN;
#pragma unroll
  for (int c2 = 0; c2 < 4; ++c2) {
    const int k8 = (c2 * 256 + t) * 8;      // 8 floats per thread-chunk
    if (k8 >= NT * 64) continue;
    float f[8];
    if (k8 + 8 <= DIN) {
#pragma unroll
      for (int h = 0; h < 4; ++h) {
        float2 v = *(const float2*)(row + k8 + h * 2);
        f[h * 2] = v.x; f[h * 2 + 1] = v.y;
      }
    } else {
#pragma unroll
      for (int h = 0; h < 8; ++h) f[h] = (k8 + h < DIN) ? row[k8 + h] : 0.f;
    }
    uint4 o;
    o.x = pack2(f[0], f[1]); o.y = pack2(f[2], f[3]);
    o.z = pack2(f[4], f[5]); o.w = pack2(f[6], f[7]);
    const int kc = k8 >> 6, kf = k8 & 63;
    char* dst = XbA + (size_t)kc * 32768 + m * 128 + ((kf * 2) ^ ((m & 7) << 4));
    *(uint4*)dst = o;
  }
}

// ---------------------------------------------------------------------------
// gemm_qk4: Out[m][n] = sum_k X[m,k]*W[n,k] + bias[n]  (bf16 out, full K)
// BM=256 BN=32 BK=64, NT=121 steps. 512 thr = 8 waves (wr=wv>>1: 64 rows,
// wc=wv&1: 16 cols). Per wave per step EXACTLY 5 VMEM instrs:
//   4x global_load_lds (A tile, L2-resident XbA, 2 steps ahead)
//   1x float4 B row-chunk (lane-contiguous 128B line), 4 steps ahead in a
//     4-deep NAMED register ring.
// Counted waits vmcnt(11)/vmcnt(1) are exact -> B queue NEVER drains.
// LDS 72KB -> 2 WGs/CU. grid (241, 2).
// ---------------------------------------------------------------------------
__global__ __launch_bounds__(512, 4)
void gemm_qk4(const char* __restrict__ XbA,
              const float* __restrict__ Wq, const float* __restrict__ Wk,
              const float* __restrict__ bq, const float* __restrict__ bk,
              unsigned short* __restrict__ Qbf, unsigned short* __restrict__ Kbf)
{
  const int mat = blockIdx.y;
  const float* W = mat ? Wk : Wq;
  const float* bias = mat ? bk : bq;
  unsigned short* Out = mat ? Kbf : Qbf;
  const int n0 = blockIdx.x * 32;
  const int tid = threadIdx.x, l = tid & 63, wv = tid >> 6;
  const int wr = wv >> 1, wc = wv & 1;
  const int lm = l & 15, hq = l >> 4;

  __shared__ __align__(16) char Abuf[2][32768];
  __shared__ __align__(16) char Bbuf[2][4096];

  // B staging: thread -> row tid>>4 (0..31), float4 at (tid&15)*4 floats
  const int brow = tid >> 4, kq = tid & 15;
  const int bn = min(n0 + brow, DIN - 1);
  const long long bbase = (long long)bn * DIN;
  const long long DD = (long long)DIN * DIN;

  float4 S0, S1, S2, S3;

#define LOADB(SET, t_) {                                                  \
    const int kc_ = min((t_), NT - 1);                                    \
    long long idx_ = bbase + kc_ * 64 + kq * 4;                           \
    if (idx_ + 4 <= DD) SET = *(const float4*)(W + idx_);                 \
    else { float4 tt_ = *(const float4*)(W + DD - 4);                     \
           SET.x = tt_.z; SET.y = tt_.w; SET.z = 0.f; SET.w = 0.f; } }

#define SWRITE(buf, SET) {                                                \
    unsigned long long pk_ = (unsigned long long)pack2(SET.x, SET.y) |    \
                     ((unsigned long long)pack2(SET.z, SET.w) << 32);     \
    *(unsigned long long*)(Bbuf[buf] + brow * 128 +                       \
        ((kq * 8) ^ ((brow & 7) << 4))) = pk_; }

#define GA(t_, buf) {                                                     \
    const int kc_ = min((t_), NT - 1);                                    \
    const char* g_ = XbA + (size_t)kc_ * 32768;                           \
    char* lb_ = Abuf[buf];                                                \
    _Pragma("unroll")                                                     \
    for (int q_ = 0; q_ < 4; ++q_) {                                      \
      const int ch_ = q_ * 8 + wv;                                        \
      gload16(g_ + ch_ * 1024 + l * 16, lb_ + ch_ * 1024);                \
    } }

  f32x4 acc[4] = {};

#define COMPUTE(buf) {                                                    \
    const char* a_ = Abuf[buf];                                           \
    const char* b_ = Bbuf[buf];                                           \
    _Pragma("unroll")                                                     \
    for (int ks_ = 0; ks_ < 2; ++ks_) {                                   \
      const int nl_ = wc * 16 + lm;                                       \
      bf16x8 bf_ = *(const bf16x8*)(b_ + nl_ * 128 +                      \
          (((ks_ * 64 + hq * 16)) ^ ((nl_ & 7) << 4)));                   \
      _Pragma("unroll")                                                   \
      for (int i_ = 0; i_ < 4; ++i_) {                                    \
        const int m_ = wr * 64 + i_ * 16 + lm;                            \
        bf16x8 af_ = *(const bf16x8*)(a_ + m_ * 128 +                     \
            (((ks_ * 64 + hq * 16)) ^ ((m_ & 7) << 4)));                  \
        acc[i_] = __builtin_amdgcn_mfma_f32_16x16x32_bf16(af_, bf_, acc[i_], 0, 0, 0); \
      }                                                                   \
    } }

#define SB()     __builtin_amdgcn_sched_barrier(0)
#define WAITV(n) { asm volatile("s_waitcnt vmcnt(" #n ")" ::: "memory"); SB(); }
#define WAITL()  { asm volatile("s_waitcnt lgkmcnt(0)" ::: "memory"); SB(); }

  // prologue: B tiles 0..3 -> S0..S3; A tile 0,1; stage tile 0
  LOADB(S0, 0) LOADB(S1, 1) LOADB(S2, 2) LOADB(S3, 3)
  GA(0, 0)
  WAITV(7)            // S0 landed (younger: S1,S2,S3 + GA0(4) = 7)
  SWRITE(0, S0)
  LOADB(S0, 4)
  GA(1, 1)
  WAITV(5)            // GA0 landed (younger: S0-refill(1) + GA1(4) = 5)
  WAITL()
  __builtin_amdgcn_s_barrier(); SB();

  // steady state per step s (consume CS = tile s+1's regs):
  //   WAITV(11): tile-(s+1) B regs ready, keeps >=2 newest steps in flight
  //   SWRITE -> Bbuf[(s+1)&1]; refill CS <- tile s+5; COMPUTE tile s;
  //   WAITV(1): A tile s+1 landed (younger: this step's BL only)
  //   barrier; GA tile s+2 -> Abuf[s&1]
#define STEP(s_, CS) {                                                    \
    WAITV(11)                                                             \
    if ((s_) + 1 < NT) SWRITE(((s_) + 1) & 1, CS)                         \
    LOADB(CS, (s_) + 5)                                                   \
    SB();                                                                 \
    COMPUTE((s_) & 1)                                                     \
    WAITV(1)                                                              \
    WAITL()                                                               \
    __builtin_amdgcn_s_barrier(); SB();                                   \
    if ((s_) + 2 < NT) GA((s_) + 2, (s_) & 1)                             \
  }

  for (int su = 0; su < NT - 1; su += 4) {
    STEP(su + 0, S1)
    STEP(su + 1, S2)
    STEP(su + 2, S3)
    STEP(su + 3, S0)
  }
  STEP(NT - 1, S1)   // s = 120
#undef STEP
#undef LOADB
#undef SWRITE
#undef GA
#undef COMPUTE
#undef WAITV
#undef WAITL
#undef SB

  // epilogue: Out[m][col] = acc + bias (bf16); col >= DIN -> 0
#pragma unroll
  for (int i = 0; i < 4; ++i) {
    const int r0 = wr * 64 + i * 16 + (l >> 4) * 4;
    const int col = n0 + wc * 16 + lm;
    const float bb = (col < DIN) ? bias[col] : 0.f;
#pragma unroll
    for (int q = 0; q < 4; ++q) {
      const float v = acc[i][q] + bb;
      Out[(size_t)(r0 + q) * KP + col] = (col < DIN) ? (unsigned short)f2b(v) : 0;
    }
  }
}

// ---------------------------------------------------------------------------
// logits partials: LP[z][m][n] = sum_{k in chunk z} Q[m,k]*K[n,k]
// ---------------------------------------------------------------------------
__global__ __launch_bounds__(512)
void gemm_logits(const unsigned short* __restrict__ Qbf,
                 const unsigned short* __restrict__ Kbf, float* __restrict__ LP)
{
  const int qr = blockIdx.x & 1, qc = blockIdx.x >> 1, z = blockIdx.z;
  const int tid = threadIdx.x, lane = tid & 63, wv = tid >> 6;
  const int lm = lane & 15, lq = (lane >> 4) * 8;
  const int rowBase = qr * 128 + (wv & 3) * 32;
  const int colBase = qc * 128 + (wv >> 2) * 64;
  const int k0 = z * 128;
  f32x4 acc[2][4] = {};
#pragma unroll
  for (int ks = 0; ks < 4; ++ks) {
    bf16x8 a[2], b[4];
#pragma unroll
    for (int i = 0; i < 2; ++i)
      a[i] = *(const bf16x8*)(Qbf + (size_t)(rowBase + i * 16 + lm) * KP + k0 + ks * 32 + lq);
#pragma unroll
    for (int j = 0; j < 4; ++j)
      b[j] = *(const bf16x8*)(Kbf + (size_t)(colBase + j * 16 + lm) * KP + k0 + ks * 32 + lq);
#pragma unroll
    for (int i = 0; i < 2; ++i)
#pragma unroll
      for (int j = 0; j < 4; ++j)
        acc[i][j] = __builtin_amdgcn_mfma_f32_16x16x32_bf16(a[i], b[j], acc[i][j], 0, 0, 0);
  }
  float* out = LP + (size_t)z * 65536;
#pragma unroll
  for (int i = 0; i < 2; ++i) {
    const int r0 = rowBase + i * 16 + (lane >> 4) * 4;
#pragma unroll
    for (int j = 0; j < 4; ++j) {
      const int col = colBase + j * 16 + lm;
#pragma unroll
      for (int q = 0; q < 4; ++q)
        out[(size_t)(r0 + q) * 256 + col] = acc[i][j][q];
    }
  }
}

// ---------------------------------------------------------------------------
// fused: sum 64 logit partials -> row softmax -> atomicAdd into abar (w/ 1/256)
// ---------------------------------------------------------------------------
__global__ void softmax_fused(const float* __restrict__ LP, float* __restrict__ abar)
{
  __shared__ float red[8];
  const int m = blockIdx.x, t = threadIdx.x;
  float v = 0.f;
#pragma unroll 8
  for (int zz = 0; zz < 64; ++zz) v += LP[(size_t)zz * 65536 + m * 256 + t];
  const float scale = 1.0f / sqrtf((float)DIN);
  float mx = v;
#pragma unroll
  for (int o = 32; o >= 1; o >>= 1) mx = fmaxf(mx, __shfl_xor(mx, o, 64));
  if ((t & 63) == 0) red[t >> 6] = mx;
  __syncthreads();
  mx = fmaxf(fmaxf(red[0], red[1]), fmaxf(red[2], red[3]));
  float e = __expf((v - mx) * scale);
  float s = e;
#pragma unroll
  for (int o = 32; o >= 1; o >>= 1) s += __shfl_xor(s, o, 64);
  if ((t & 63) == 0) red[4 + (t >> 6)] = s;
  __syncthreads();
  s = red[4] + red[5] + red[6] + red[7];
  atomicAdd(&abar[t], e * (1.0f / 256.0f) / s);
}

// y[c] = sum_m abar[m] * X[m][c]
__global__ void y_kernel(const float* __restrict__ X, const float* __restrict__ abar,
                         float* __restrict__ y)
{
  __shared__ float ab[256];
  ab[threadIdx.x] = abar[threadIdx.x];
  __syncthreads();
  const int c = blockIdx.x * 256 + threadIdx.x;
  if (c >= DIN) return;
  float s = 0.f;
#pragma unroll 8
  for (int m = 0; m < 256; ++m) s += ab[m] * X[(size_t)m * DIN + c];
  y[c] = s;
}

// ctx[d] = Wv[d,:]·y + bv[d] — one row per wave, lane-contiguous float2 stream
__global__ __launch_bounds__(512)
void ctx_mv(const float* __restrict__ Wv, const float* __restrict__ y,
            const float* __restrict__ bv, float* __restrict__ ctx)
{
  const int wv = threadIdx.x >> 6, l = threadIdx.x & 63;
  const int row = blockIdx.x * 8 + wv;
  if (row >= DIN) return;
  const float* wr_ = Wv + (size_t)row * DIN;
  float s = 0.f;
#pragma unroll 4
  for (int it = 0; it < 61; ++it) {
    const int k = it * 128 + l * 2;
    if (k < DIN) {
      float2 w2 = *(const float2*)(wr_ + k);
      float2 y2 = *(const float2*)(y + k);
      s = fmaf(w2.x, y2.x, s);
      s = fmaf(w2.y, y2.y, s);
    }
  }
#pragma unroll
  for (int o = 32; o >= 1; o >>= 1) s += __shfl_xor(s, o, 64);
  if (l == 0) ctx[row] = s + bv[row];
}

// base[j] += sum_{i in chunk} ctx[i] * (mu+sg*ep)[i][DIN+j]
__global__ void base_kernel(const float* __restrict__ mu, const float* __restrict__ sg,
                            const float* __restrict__ ep, const float* __restrict__ ctx,
                            float* __restrict__ base)
{
  const int j = threadIdx.x;
  if (j >= HOUT) return;
  const int i0 = blockIdx.x * 31;
  const int i1 = min(i0 + 31, DIN);
  float acc = 0.f;
#pragma unroll 4
  for (int i = i0; i < i1; ++i) {
    const size_t idx = (size_t)i * NNODE + DIN + j;
    acc = fmaf(ctx[i], fmaf(sg[idx], ep[idx], mu[idx]), acc);
  }
  atomicAdd(&base[j], acc);
}

// WsG[t][j] = (mu+sg*ep)[DIN+t][DIN+j]
__global__ void ws_kernel(const float* __restrict__ mu, const float* __restrict__ sg,
                          const float* __restrict__ ep, float* __restrict__ WsG)
{
  const int t = blockIdx.x;
  const int j = threadIdx.x;
  if (j >= HOUT) return;
  const size_t idx = (size_t)(DIN + t) * NNODE + DIN + j;
  WsG[t * HOUT + j] = fmaf(sg[idx], ep[idx], mu[idx]);
}

// ---------------------------------------------------------------------------
// scan2: latency-minimal sequential NEAT scan. 1 wave.
// ---------------------------------------------------------------------------
__global__ __launch_bounds__(64, 1)
void scan2(const float* __restrict__ WsG, const float* __restrict__ base,
           const float* __restrict__ bmu, const float* __restrict__ bsg,
           const float* __restrict__ epb, float* __restrict__ out)
{
  __shared__ __align__(16) float tile[32 * HOUT + 128];
  const int l = threadIdx.x;

  float a0, a1, a2, a3, a4;
  {
    int j = l;       a0 = base[j] + bmu[j] + bsg[j] * epb[j];
    j = l + 64;      a1 = base[j] + bmu[j] + bsg[j] * epb[j];
    j = l + 128;     a2 = base[j] + bmu[j] + bsg[j] * epb[j];
    j = l + 192;     a3 = base[j] + bmu[j] + bsg[j] * epb[j];
    j = l + 256;     a4 = (j < HOUT) ? (base[j] + bmu[j] + bsg[j] * epb[j]) : 0.f;
  }

  float4 stg[33];
  auto LOADT = [&](int tb) {
    const int nfl = ((tb == 8) ? 4 : 32) * HOUT;
    const float* src = WsG + tb * 32 * HOUT;
#pragma unroll
    for (int c = 0; c < 33; ++c) {
      const int o = c * 256 + l * 4;
      if (o < nfl) stg[c] = *(const float4*)(src + o);
    }
  };
  auto WRITET = [&](int tb) {
    const int nfl = ((tb == 8) ? 4 : 32) * HOUT;
#pragma unroll
    for (int c = 0; c < 33; ++c) {
      const int o = c * 256 + l * 4;
      if (o < nfl) *(float4*)&tile[o] = stg[c];
    }
  };

  float w0, w1, w2, w3, w4;
  auto PRER = [&](int trow) {
    const float* tr = tile + trow * HOUT;
    w0 = tr[l]; w1 = tr[l + 64]; w2 = tr[l + 128]; w3 = tr[l + 192]; w4 = tr[l + 256];
  };

  auto inner = [&](auto Bc, int tb, int nrows) {
    constexpr int B = Bc.value;
    for (int tt = 0; tt < nrows; ++tt) {
      const int t = tb * 32 + tt;
      float pre;
      if constexpr (B == 0) pre = readlane_f(a0, t & 63);
      else if constexpr (B == 1) pre = readlane_f(a1, t & 63);
      else if constexpr (B == 2) pre = readlane_f(a2, t & 63);
      else if constexpr (B == 3) pre = readlane_f(a3, t & 63);
      else pre = readlane_f(a4, t & 63);
      const float pc = fminf(fmaxf(pre, -12.f), 12.f);
      const float e = __expf(2.f * pc);
      const float vt = 1.f - 2.f / (e + 1.f);
      if (t >= 256 && l == 0) out[t - 256] = vt;
      if (l > t)            a0 = fmaf(vt, w0, a0);
      if (l + 64 > t)       a1 = fmaf(vt, w1, a1);
      if (l + 128 > t)      a2 = fmaf(vt, w2, a2);
      if (l + 192 > t)      a3 = fmaf(vt, w3, a3);
      if (l + 256 > t && l + 256 < HOUT) a4 = fmaf(vt, w4, a4);
      if (tt + 1 < nrows) PRER(tt + 1);
    }
  };

  LOADT(0); WRITET(0); PRER(0);

#define TILE_STEP(tb, B, nr)                                    \
  { if ((tb) < 8) LOADT((tb) + 1);                              \
    inner(std::integral_constant<int, B>{}, (tb), (nr));        \
    if ((tb) < 8) { WRITET((tb) + 1); PRER(0); } }

  TILE_STEP(0, 0, 32)
  TILE_STEP(1, 0, 32)
  TILE_STEP(2, 1, 32)
  TILE_STEP(3, 1, 32)
  TILE_STEP(4, 2, 32)
  TILE_STEP(5, 2, 32)
  TILE_STEP(6, 3, 32)
  TILE_STEP(7, 3, 32)
  TILE_STEP(8, 4, 4)
#undef TILE_STEP
}

// ---------------------------------------------------------------------------
extern "C" void kernel_launch(void* const* d_in, const int* in_sizes, int n_in,
                              void* d_out, int out_size, void* d_ws, size_t ws_size,
                              hipStream_t stream)
{
  const float* X   = (const float*)d_in[0];
  const float* Wq  = (const float*)d_in[1];
  const float* bq  = (const float*)d_in[2];
  const float* Wk  = (const float*)d_in[3];
  const float* bk  = (const float*)d_in[4];
  const float* Wv  = (const float*)d_in[5];
  const float* bv  = (const float*)d_in[6];
  const float* wmu = (const float*)d_in[7];
  const float* wsg = (const float*)d_in[8];
  const float* bmu = (const float*)d_in[9];
  const float* bsg = (const float*)d_in[10];
  const float* epw = (const float*)d_in[11];
  const float* epb = (const float*)d_in[12];

  char* p = (char*)d_ws;
  auto alloc = [&](size_t bytes) -> char* {
    char* r = p;
    p += (bytes + 255) & ~(size_t)255;
    return r;
  };
  char* XbA = alloc((size_t)NT * 32768);                       // ~3.9MB swizzled
  unsigned short* Qbf = (unsigned short*)alloc((size_t)256 * KP * 2);
  unsigned short* Kbf = (unsigned short*)alloc((size_t)256 * KP * 2);
  float* LP   = (float*)alloc((size_t)64 * 65536 * 4);
  float* abar = (float*)alloc(256 * 4);
  float* y    = (float*)alloc(7686 * 4);
  float* ctx  = (float*)alloc(7686 * 4);
  float* base = (float*)alloc(HOUT * 4);
  float* WsG  = (float*)alloc((size_t)HOUT * HOUT * 4 + 1024);

  prep_x3<<<dim3(256), dim3(256), 0, stream>>>(X, XbA);
  hipMemsetAsync(abar, 0, 256 * 4, stream);
  hipMemsetAsync(base, 0, HOUT * 4, stream);
  hipMemsetAsync(Qbf, 0, (size_t)256 * KP * 2, stream);
  hipMemsetAsync(Kbf, 0, (size_t)256 * KP * 2, stream);

  gemm_qk4<<<dim3(241, 2), dim3(512), 0, stream>>>(XbA, Wq, Wk, bq, bk, Qbf, Kbf);
  gemm_logits<<<dim3(4, 1, 64), dim3(512), 0, stream>>>(Qbf, Kbf, LP);
  softmax_fused<<<dim3(256), dim3(256), 0, stream>>>(LP, abar);
  y_kernel<<<dim3(31), dim3(256), 0, stream>>>(X, abar, y);
  ctx_mv<<<dim3(961), dim3(512), 0, stream>>>(Wv, y, bv, ctx);
  base_kernel<<<dim3(256), dim3(320), 0, stream>>>(wmu, wsg, epw, ctx, base);
  ws_kernel<<<dim3(260), dim3(320), 0, stream>>>(wmu, wsg, epw, WsG);
  scan2<<<dim3(1), dim3(64), 0, stream>>>(WsG, base, bmu, bsg, epb, (float*)d_out);
}